// Round 7
// baseline (833.097 us; speedup 1.0000x reference)
//
#include <hip/hip_runtime.h>
#include <stdint.h>

#define P_PAIRS 3486
#define NNODES 84
#define HSZ 2048
#define H2SZ 1024
#define G3H 6144
#define LN_EPS 1e-5f

typedef short bf16x8 __attribute__((ext_vector_type(8)));
typedef float f32x4 __attribute__((ext_vector_type(4)));

typedef __attribute__((address_space(3))) unsigned int lds_uint;
typedef __attribute__((address_space(1))) const unsigned int global_cuint;

// s_waitcnt immediate (gfx9 encoding): vmcnt[3:0]+[15:14], expcnt[6:4], lgkmcnt[11:8]
#define WAIT_VM(n) __builtin_amdgcn_s_waitcnt(0x0F00 | 0x70 | ((n) & 0xF) | (((n) >> 4) << 14))

__device__ __forceinline__ unsigned short f2bf(float f) {
    unsigned int u = __float_as_uint(f);
    return (unsigned short)((u + 0x7fffu + ((u >> 16) & 1u)) >> 16);
}
__device__ __forceinline__ float bf2f(unsigned short s) {
    return __uint_as_float(((unsigned int)s) << 16);
}
__device__ __forceinline__ float sigm(float x) {
    return 1.f / (1.f + expf(-x));
}

// ---- merged prep: 5x fp32->bf16 converts + pair indices + acc zero + gi ----
#define S_WHH (G3H * HSZ / 4)
#define S_W1  (HSZ * HSZ / 4)
#define S_W2  (H2SZ * HSZ / 4)
#define S_W3  (H2SZ * H2SZ / 4)
#define S_HID (P_PAIRS * HSZ / 4)
#define B0 (S_WHH)
#define B1 (B0 + S_W1)
#define B2 (B1 + S_W2)
#define B3 (B2 + S_W3)
#define B4 (B3 + S_HID)

__device__ __forceinline__ void cvt4(const float4* in, ushort4* out, int i) {
    float4 v = in[i];
    ushort4 o;
    o.x = f2bf(v.x); o.y = f2bf(v.y); o.z = f2bf(v.z); o.w = f2bf(v.w);
    out[i] = o;
}

__global__ void k_prep(const float4* __restrict__ Whh, ushort4* __restrict__ whh_b,
                       const float4* __restrict__ W1, ushort4* __restrict__ w1_b,
                       const float4* __restrict__ W2, ushort4* __restrict__ w2_b,
                       const float4* __restrict__ W3, ushort4* __restrict__ w3_b,
                       const float4* __restrict__ hid, ushort4* __restrict__ hid_b,
                       int* __restrict__ ip, int* __restrict__ jp, float* __restrict__ acc,
                       const float* __restrict__ x, const float* __restrict__ Wih,
                       const float* __restrict__ bih, float* __restrict__ gi) {
    const int tid0 = blockIdx.x * blockDim.x + threadIdx.x;
    const int stride = gridDim.x * blockDim.x;
    int idx = tid0;
    if (idx < 8) acc[idx] = 0.f;
    if (idx < P_PAIRS) {
        int i = 0, rem = idx;
        while (rem >= NNODES - 1 - i) { rem -= NNODES - 1 - i; ++i; }
        ip[idx] = i;
        jp[idx] = i + 1 + rem;
    }
    for (; idx < B4; idx += stride) {
        if (idx < B0)      cvt4(Whh, whh_b, idx);
        else if (idx < B1) cvt4(W1, w1_b, idx - B0);
        else if (idx < B2) cvt4(W2, w2_b, idx - B1);
        else if (idx < B3) cvt4(W3, w3_b, idx - B2);
        else               cvt4(hid, hid_b, idx - B3);
    }
    // gi = x @ Wih.T + bih  [84, 6144]
    for (int g = tid0; g < NNODES * G3H; g += stride) {
        int node = g / G3H, n = g - node * G3H;
        const float* xr = x + node * 64;
        const float* wr = Wih + (size_t)n * 64;
        float s = bih[n];
#pragma unroll
        for (int k = 0; k < 64; ++k) s += xr[k] * wr[k];
        gi[g] = s;
    }
}

// ---------------- bf16 MFMA GEMM, distance-2 pipelined ----------------
// C[M,N] = act(A[M,K] @ B[N,K]^T + bias). 128x128 block tile, 4 waves of
// 64x64. Block-SHARED double-buffered LDS (2 x 16 KB). Per iteration:
//   compute tile k from buf[cur]  ->  s_barrier (reads done)
//   -> issue DMA tile k+2 into buf[cur]  ->  s_waitcnt vmcnt(4)
//      (waits on tile k+1's DMAs, issued ONE ITERATION AGO; k+2 stays
//       in flight)  ->  s_barrier (tile k+1 staged for everyone).
// Raw s_barrier avoids __syncthreads' implicit vmcnt(0) drain — the ~900-cyc
// HBM-line latency is absorbed by one iteration of MFMA instead of stalling.
__global__ __launch_bounds__(256)
void k_gemm(const unsigned short* __restrict__ A, const unsigned short* __restrict__ B,
            const float* __restrict__ bias, float* __restrict__ Cf,
            unsigned short* __restrict__ Cb,
            int M, int N, int K, int relu, float* __restrict__ accg, int redslot) {
    __shared__ __align__(16) unsigned short lsA[2][128 * 32];   // 2 x 8 KB
    __shared__ __align__(16) unsigned short lsB[2][128 * 32];   // 2 x 8 KB
    const int m0 = blockIdx.x * 128;
    const int n0 = blockIdx.y * 128;
    const int tid = threadIdx.x;
    const int lane = tid & 63;
    const int wave = tid >> 6;
    const int wr = (wave >> 1) * 64;   // wave row offset in tile
    const int wc = (wave & 1) * 64;    // wave col offset in tile
    const int fr = lane & 15;          // A-m / B-n / D-col within 16x16 frag
    const int quad = lane >> 4;
    const int kof = quad * 8;

    f32x4 acc[4][4];
#pragma unroll
    for (int i = 0; i < 4; ++i)
#pragma unroll
        for (int j = 0; j < 4; ++j) {
            f32x4 z = {0.f, 0.f, 0.f, 0.f};
            acc[i][j] = z;
        }

    // Staging geometry: tile = 128 rows x 64 B; wave DMAs two 1-KB chunks per
    // matrix; LDS dest = wave-uniform base + lane*16 (HW rule).
    const int lin0 = (wave * 2) * 1024 + lane * 16;
    const int lin1 = lin0 + 1024;
    const int row0 = lin0 >> 6, col0 = (lin0 & 63) >> 1;   // shorts
    const int row1 = lin1 >> 6, col1 = (lin1 & 63) >> 1;
    int ga0 = m0 + row0; if (ga0 >= M) ga0 = M - 1;        // clamp; rows >= M never stored
    int ga1 = m0 + row1; if (ga1 >= M) ga1 = M - 1;
    const int gb0 = n0 + row0, gb1 = n0 + row1;            // N % 128 == 0

    const unsigned short* pa0 = A + (size_t)ga0 * K + col0;
    const unsigned short* pa1 = A + (size_t)ga1 * K + col1;
    const unsigned short* pb0 = B + (size_t)gb0 * K + col0;
    const unsigned short* pb1 = B + (size_t)gb1 * K + col1;
    const int ch0 = (wave * 2) * 512;   // chunk offsets within a panel (shorts)
    const int ch1 = ch0 + 512;

    auto dma_tile = [&](int k0, int b) {
        __builtin_amdgcn_global_load_lds((global_cuint*)(pa0 + k0), (lds_uint*)&lsA[b][ch0], 16, 0, 0);
        __builtin_amdgcn_global_load_lds((global_cuint*)(pa1 + k0), (lds_uint*)&lsA[b][ch1], 16, 0, 0);
        __builtin_amdgcn_global_load_lds((global_cuint*)(pb0 + k0), (lds_uint*)&lsB[b][ch0], 16, 0, 0);
        __builtin_amdgcn_global_load_lds((global_cuint*)(pb1 + k0), (lds_uint*)&lsB[b][ch1], 16, 0, 0);
    };

    // Prologue: tiles 0 and 1 in flight; wait only for tile 0 (vmcnt(4)).
    dma_tile(0, 0);
    dma_tile(32, 1);
    WAIT_VM(4);
    __builtin_amdgcn_s_barrier();

    const int T = K >> 5;
    for (int it = 0; it < T; ++it) {
        const int cur = it & 1;
        bf16x8 av[4], bv[4];
#pragma unroll
        for (int mi = 0; mi < 4; ++mi)
            av[mi] = *(const bf16x8*)(&lsA[cur][(wr + mi * 16 + fr) * 32 + kof]);
#pragma unroll
        for (int ni = 0; ni < 4; ++ni)
            bv[ni] = *(const bf16x8*)(&lsB[cur][(wc + ni * 16 + fr) * 32 + kof]);
#pragma unroll
        for (int mi = 0; mi < 4; ++mi)
#pragma unroll
            for (int ni = 0; ni < 4; ++ni)
                acc[mi][ni] = __builtin_amdgcn_mfma_f32_16x16x32_bf16(av[mi], bv[ni], acc[mi][ni], 0, 0, 0);
        __builtin_amdgcn_s_barrier();            // everyone done reading buf[cur]
        const int kpre = (it + 2) << 5;
        if (kpre < K) {
            dma_tile(kpre, cur);                  // overwrite buf[cur] with tile k+2
            WAIT_VM(4);                           // tile k+1 (issued last iter) done
        } else if (it + 1 < T) {
            WAIT_VM(0);                           // final tile: full drain once
        }
        __builtin_amdgcn_s_barrier();            // tile k+1 staged for all waves
    }

    float s1 = 0.f, s2 = 0.f;
#pragma unroll
    for (int mi = 0; mi < 4; ++mi) {
#pragma unroll
        for (int r = 0; r < 4; ++r) {
            int row = m0 + wr + mi * 16 + quad * 4 + r;   // D: row = quad*4 + reg
            if (row >= M) continue;
#pragma unroll
            for (int ni = 0; ni < 4; ++ni) {
                int col = n0 + wc + ni * 16 + fr;          // D: col = lane & 15
                float v = acc[mi][ni][r];
                if (bias) v += bias[col];
                if (relu) v = fmaxf(v, 0.f);
                if (redslot >= 0) { s1 += v; s2 += v * v; }
                if (Cb) Cb[(size_t)row * N + col] = f2bf(v);
                else    Cf[(size_t)row * N + col] = v;
            }
        }
    }

    if (redslot >= 0) {
        __syncthreads();
        float* sm = (float*)&lsA[0][0];
        sm[tid] = s1;
        sm[256 + tid] = s2;
        __syncthreads();
        for (int o = 128; o > 0; o >>= 1) {
            if (tid < o) {
                sm[tid] += sm[tid + o];
                sm[256 + tid] += sm[256 + tid + o];
            }
            __syncthreads();
        }
        if (tid == 0) {
            atomicAdd(&accg[redslot * 2], sm[0]);
            atomicAdd(&accg[redslot * 2 + 1], sm[256]);
        }
    }
}

// ---------------- GRU gate combine (gh in bf16), vectorized ----------------
__global__ void k_combine(const float4* __restrict__ gi, const ushort4* __restrict__ gh,
                          const int* __restrict__ pair, const float4* __restrict__ hprev_f,
                          const ushort4* __restrict__ hprev_b,
                          ushort4* __restrict__ hout) {
    int idx = blockIdx.x * blockDim.x + threadIdx.x;       // 4-elem units
    if (idx >= P_PAIRS * (HSZ / 4)) return;
    int p = idx >> 9;                                       // HSZ/4 = 512
    int c4 = idx & 511;
    int node = pair[p];
    const float4* gip = gi + (size_t)node * (G3H / 4) + c4;
    const ushort4* ghp = gh + (size_t)p * (G3H / 4) + c4;
    float4 gir = gip[0],   giz = gip[512], gin = gip[1024];
    ushort4 ghr4 = ghp[0], ghz4 = ghp[512], ghn4 = ghp[1024];
    float hr[4] = {bf2f(ghr4.x), bf2f(ghr4.y), bf2f(ghr4.z), bf2f(ghr4.w)};
    float hz[4] = {bf2f(ghz4.x), bf2f(ghz4.y), bf2f(ghz4.z), bf2f(ghz4.w)};
    float hn[4] = {bf2f(ghn4.x), bf2f(ghn4.y), bf2f(ghn4.z), bf2f(ghn4.w)};
    float hp[4];
    if (hprev_f) {
        float4 h = hprev_f[idx];
        hp[0] = h.x; hp[1] = h.y; hp[2] = h.z; hp[3] = h.w;
    } else {
        ushort4 h = hprev_b[idx];
        hp[0] = bf2f(h.x); hp[1] = bf2f(h.y); hp[2] = bf2f(h.z); hp[3] = bf2f(h.w);
    }
    float ir[4] = {gir.x, gir.y, gir.z, gir.w};
    float iz[4] = {giz.x, giz.y, giz.z, giz.w};
    float in_[4] = {gin.x, gin.y, gin.z, gin.w};
    unsigned short o[4];
#pragma unroll
    for (int q = 0; q < 4; ++q) {
        float r = sigm(ir[q] + hr[q]);
        float z = sigm(iz[q] + hz[q]);
        float nn = tanhf(in_[q] + r * hn[q]);
        o[q] = f2bf((1.f - z) * nn + z * hp[q]);
    }
    ushort4 ov = {o[0], o[1], o[2], o[3]};
    hout[idx] = ov;
}

// ---------------- apply full-tensor LN, float4 vectorized, emit bf16 ----------------
__global__ void k_lnapply(const float4* __restrict__ t, const float4* __restrict__ w,
                          const float4* __restrict__ b, const float* __restrict__ acc, int slot,
                          int n, ushort4* __restrict__ out) {
    float cnt = (float)n;
    float mu = acc[slot * 2] / cnt;
    float var = acc[slot * 2 + 1] / cnt - mu * mu;
    float inv = rsqrtf(var + LN_EPS);
    int n4 = n >> 2;
    int idx = blockIdx.x * blockDim.x + threadIdx.x;
    int stride = gridDim.x * blockDim.x;
    for (; idx < n4; idx += stride) {
        float4 tv = t[idx], wv = w[idx], bv = b[idx];
        ushort4 o;
        o.x = f2bf((tv.x - mu) * inv * wv.x + bv.x);
        o.y = f2bf((tv.y - mu) * inv * wv.y + bv.y);
        o.z = f2bf((tv.z - mu) * inv * wv.z + bv.z);
        o.w = f2bf((tv.w - mu) * inv * wv.w + bv.w);
        out[idx] = o;
    }
}

// ---------------- head: LN3 fused + sigmoid(W4 . h + b4), one wave per row ----------------
__global__ void k_head(const float* __restrict__ t, const float* __restrict__ w,
                       const float* __restrict__ b, const float* __restrict__ accv,
                       const float* __restrict__ W4, const float* __restrict__ b4,
                       float* __restrict__ vals) {
    float cnt = (float)P_PAIRS * (float)H2SZ;
    float mu = accv[4] / cnt;
    float var = accv[5] / cnt - mu * mu;
    float inv = rsqrtf(var + LN_EPS);
    int wid = (blockIdx.x * blockDim.x + threadIdx.x) >> 6;
    int lane = threadIdx.x & 63;
    if (wid >= P_PAIRS) return;
    const float* row = t + (size_t)wid * H2SZ;
    const float* wrp = w + (size_t)wid * H2SZ;
    const float* brp = b + (size_t)wid * H2SZ;
    float s = 0.f;
    for (int k = lane; k < H2SZ; k += 64)
        s += ((row[k] - mu) * inv * wrp[k] + brp[k]) * W4[k];
#pragma unroll
    for (int o = 32; o > 0; o >>= 1) s += __shfl_down(s, o, 64);
    if (lane == 0) vals[wid] = sigm(s + b4[0]);
}

// ---------------- scatter to symmetric 84x84 ----------------
__global__ void k_out(const float* __restrict__ vals, float* __restrict__ out) {
    int idx = blockIdx.x * blockDim.x + threadIdx.x;
    if (idx >= NNODES * NNODES) return;
    int r = idx / NNODES, c = idx - r * NNODES;
    if (r == c) { out[idx] = 0.f; return; }
    int i = r < c ? r : c, j = r < c ? c : r;
    int p = i * (NNODES - 1) - i * (i - 1) / 2 + (j - i - 1);
    out[idx] = vals[p];
}

extern "C" void kernel_launch(void* const* d_in, const int* in_sizes, int n_in,
                              void* d_out, int out_size, void* d_ws, size_t ws_size,
                              hipStream_t stream) {
    const float* x    = (const float*)d_in[0];
    const float* hid  = (const float*)d_in[1];
    const float* Wih  = (const float*)d_in[2];
    const float* Whh  = (const float*)d_in[3];
    const float* bih  = (const float*)d_in[4];
    const float* bhh  = (const float*)d_in[5];
    const float* W1   = (const float*)d_in[6];
    const float* b1   = (const float*)d_in[7];
    const float* ln1w = (const float*)d_in[8];
    const float* ln1b = (const float*)d_in[9];
    const float* W2   = (const float*)d_in[10];
    const float* b2   = (const float*)d_in[11];
    const float* ln2w = (const float*)d_in[12];
    const float* ln2b = (const float*)d_in[13];
    const float* W3   = (const float*)d_in[14];
    const float* b3   = (const float*)d_in[15];
    const float* ln3w = (const float*)d_in[16];
    const float* ln3b = (const float*)d_in[17];
    const float* W4   = (const float*)d_in[18];
    const float* b4   = (const float*)d_in[19];
    float* out = (float*)d_out;

    char* ws = (char*)d_ws;
    size_t off = 0;
    auto alloc = [&](size_t bytes) -> void* {
        off = (off + 255) & ~(size_t)255;
        void* p = ws + off;
        off += bytes;
        return p;
    };

    float* acc            = (float*)alloc(8 * sizeof(float));
    int*   ip             = (int*)alloc(P_PAIRS * sizeof(int));
    int*   jp             = (int*)alloc(P_PAIRS * sizeof(int));
    float* gi             = (float*)alloc((size_t)NNODES * G3H * sizeof(float));
    unsigned short* whh_b = (unsigned short*)alloc((size_t)G3H * HSZ * 2);
    unsigned short* w1_b  = (unsigned short*)alloc((size_t)HSZ * HSZ * 2);
    unsigned short* w2_b  = (unsigned short*)alloc((size_t)H2SZ * HSZ * 2);
    unsigned short* w3_b  = (unsigned short*)alloc((size_t)H2SZ * H2SZ * 2);
    unsigned short* hid_b = (unsigned short*)alloc((size_t)P_PAIRS * HSZ * 2); // reused as LN bf16 buf
    unsigned short* hbuf  = (unsigned short*)alloc((size_t)P_PAIRS * HSZ * 2); // h1 then h2 (in-place)
    unsigned short* gh    = (unsigned short*)alloc((size_t)P_PAIRS * G3H * 2); // bf16 gates
    float* t              = (float*)alloc((size_t)P_PAIRS * HSZ * sizeof(float)); // fp32 LN input
    float* vals           = (float*)alloc((size_t)P_PAIRS * sizeof(float));
    (void)ws_size; (void)in_sizes; (void)n_in; (void)out_size;

    unsigned short* lnb = hid_b; // alias: hid_b consumed (GEMM #1) before LN1 apply

    k_prep<<<2048, 256, 0, stream>>>((const float4*)Whh, (ushort4*)whh_b,
                                     (const float4*)W1, (ushort4*)w1_b,
                                     (const float4*)W2, (ushort4*)w2_b,
                                     (const float4*)W3, (ushort4*)w3_b,
                                     (const float4*)hid, (ushort4*)hid_b,
                                     ip, jp, acc, x, Wih, bih, gi);

    dim3 gBig((P_PAIRS + 127) / 128, G3H / 128);   // 28 x 48
    dim3 g3((P_PAIRS + 127) / 128, HSZ / 128);     // 28 x 16
    dim3 g4((P_PAIRS + 127) / 128, H2SZ / 128);    // 28 x 8
    int cgrid = (P_PAIRS * HSZ / 4 + 255) / 256;

    // GRU step 1: gh = hid @ Whh^T + bhh (bf16 out)
    k_gemm<<<gBig, 256, 0, stream>>>(hid_b, whh_b, bhh, nullptr, gh, P_PAIRS, G3H, HSZ, 0, acc, -1);
    k_combine<<<cgrid, 256, 0, stream>>>((const float4*)gi, (const ushort4*)gh, ip,
                                         (const float4*)hid, nullptr, (ushort4*)hbuf);
    // GRU step 2: gh = h1 @ Whh^T + bhh (bf16 out)
    k_gemm<<<gBig, 256, 0, stream>>>(hbuf, whh_b, bhh, nullptr, gh, P_PAIRS, G3H, HSZ, 0, acc, -1);
    k_combine<<<cgrid, 256, 0, stream>>>((const float4*)gi, (const ushort4*)gh, jp,
                                         nullptr, (const ushort4*)hbuf, (ushort4*)hbuf);

    // Layer 1: t = relu(h2 @ W1^T + b1); sum/sumsq fused; LN -> lnb (bf16)
    k_gemm<<<g3, 256, 0, stream>>>(hbuf, w1_b, b1, t, nullptr, P_PAIRS, HSZ, HSZ, 1, acc, 0);
    k_lnapply<<<2048, 256, 0, stream>>>((const float4*)t, (const float4*)ln1w, (const float4*)ln1b,
                                        acc, 0, P_PAIRS * HSZ, (ushort4*)lnb);

    // Layer 2
    k_gemm<<<g4, 256, 0, stream>>>(lnb, w2_b, b2, t, nullptr, P_PAIRS, H2SZ, HSZ, 1, acc, 1);
    k_lnapply<<<2048, 256, 0, stream>>>((const float4*)t, (const float4*)ln2w, (const float4*)ln2b,
                                        acc, 1, P_PAIRS * H2SZ, (ushort4*)lnb);

    // Layer 3
    k_gemm<<<g4, 256, 0, stream>>>(lnb, w3_b, b3, t, nullptr, P_PAIRS, H2SZ, H2SZ, 1, acc, 2);

    // Head: LN3 fused in fp32 + W4 matvec + sigmoid
    k_head<<<(P_PAIRS * 64 + 255) / 256, 256, 0, stream>>>(t, ln3w, ln3b, acc, W4, b4, vals);

    // Symmetric scatter
    k_out<<<(NNODES * NNODES + 255) / 256, 256, 0, stream>>>(vals, out);
}

// Round 8
// 745.718 us; speedup vs baseline: 1.1172x; 1.1172x over previous
//
#include <hip/hip_runtime.h>
#include <stdint.h>

#define P_PAIRS 3486
#define NNODES 84
#define HSZ 2048
#define H2SZ 1024
#define G3H 6144
#define LN_EPS 1e-5f

typedef short bf16x8 __attribute__((ext_vector_type(8)));
typedef float f32x4 __attribute__((ext_vector_type(4)));

typedef __attribute__((address_space(3))) unsigned int lds_uint;
typedef __attribute__((address_space(1))) const unsigned int global_cuint;

__device__ __forceinline__ unsigned short f2bf(float f) {
    unsigned int u = __float_as_uint(f);
    return (unsigned short)((u + 0x7fffu + ((u >> 16) & 1u)) >> 16);
}
__device__ __forceinline__ float bf2f(unsigned short s) {
    return __uint_as_float(((unsigned int)s) << 16);
}
__device__ __forceinline__ float sigm(float x) {
    return 1.f / (1.f + expf(-x));
}

// ---- merged prep: 5x fp32->bf16 converts + pair indices + acc zero + gi ----
#define S_WHH (G3H * HSZ / 4)
#define S_W1  (HSZ * HSZ / 4)
#define S_W2  (H2SZ * HSZ / 4)
#define S_W3  (H2SZ * H2SZ / 4)
#define S_HID (P_PAIRS * HSZ / 4)
#define B0 (S_WHH)
#define B1 (B0 + S_W1)
#define B2 (B1 + S_W2)
#define B3 (B2 + S_W3)
#define B4 (B3 + S_HID)

__device__ __forceinline__ void cvt4(const float4* in, ushort4* out, int i) {
    float4 v = in[i];
    ushort4 o;
    o.x = f2bf(v.x); o.y = f2bf(v.y); o.z = f2bf(v.z); o.w = f2bf(v.w);
    out[i] = o;
}

__global__ void k_prep(const float4* __restrict__ Whh, ushort4* __restrict__ whh_b,
                       const float4* __restrict__ W1, ushort4* __restrict__ w1_b,
                       const float4* __restrict__ W2, ushort4* __restrict__ w2_b,
                       const float4* __restrict__ W3, ushort4* __restrict__ w3_b,
                       const float4* __restrict__ hid, ushort4* __restrict__ hid_b,
                       int* __restrict__ ip, int* __restrict__ jp, float* __restrict__ acc,
                       const float* __restrict__ x, const float* __restrict__ Wih,
                       const float* __restrict__ bih, float* __restrict__ gi) {
    const int tid0 = blockIdx.x * blockDim.x + threadIdx.x;
    const int stride = gridDim.x * blockDim.x;
    int idx = tid0;
    if (idx < 8) acc[idx] = 0.f;
    if (idx < P_PAIRS) {
        int i = 0, rem = idx;
        while (rem >= NNODES - 1 - i) { rem -= NNODES - 1 - i; ++i; }
        ip[idx] = i;
        jp[idx] = i + 1 + rem;
    }
    for (; idx < B4; idx += stride) {
        if (idx < B0)      cvt4(Whh, whh_b, idx);
        else if (idx < B1) cvt4(W1, w1_b, idx - B0);
        else if (idx < B2) cvt4(W2, w2_b, idx - B1);
        else if (idx < B3) cvt4(W3, w3_b, idx - B2);
        else               cvt4(hid, hid_b, idx - B3);
    }
    // gi = x @ Wih.T + bih  [84, 6144]
    for (int g = tid0; g < NNODES * G3H; g += stride) {
        int node = g / G3H, n = g - node * G3H;
        const float* xr = x + node * 64;
        const float* wr = Wih + (size_t)n * 64;
        float s = bih[n];
#pragma unroll
        for (int k = 0; k < 64; ++k) s += xr[k] * wr[k];
        gi[g] = s;
    }
}

// ---------------- bf16 MFMA GEMM: C[M,N] = act(A[M,K] @ B[N,K]^T + bias) ----------------
// 128x128 block tile, 4 waves of 64x64 (4x4 16x16x32 frags). BK=32, 16 KB LDS,
// block-shared global_load_lds width=16 staging (best-measured config).
// __launch_bounds__(256,4): cap unified VGPR+AGPR at 128/wave -> 4 blocks/CU
// (was 136 regs -> 3 blocks/CU; per-wave MFMA duty ~7%, so MfmaUtil scales
// with resident waves). Optional fused sum/sumsq; optional bf16 out (Cb).
__global__ __launch_bounds__(256, 4)
void k_gemm(const unsigned short* __restrict__ A, const unsigned short* __restrict__ B,
            const float* __restrict__ bias, float* __restrict__ Cf,
            unsigned short* __restrict__ Cb,
            int M, int N, int K, int relu, float* __restrict__ accg, int redslot) {
    __shared__ __align__(16) unsigned short lsA[128 * 32];   // 8 KB
    __shared__ __align__(16) unsigned short lsB[128 * 32];   // 8 KB
    const int m0 = blockIdx.x * 128;
    const int n0 = blockIdx.y * 128;
    const int tid = threadIdx.x;
    const int lane = tid & 63;
    const int wave = tid >> 6;
    const int wr = (wave >> 1) * 64;   // wave row offset in tile
    const int wc = (wave & 1) * 64;    // wave col offset in tile
    const int fr = lane & 15;          // A-m / B-n / D-col within 16x16 frag
    const int quad = lane >> 4;
    const int kof = quad * 8;

    f32x4 acc[4][4];
#pragma unroll
    for (int i = 0; i < 4; ++i)
#pragma unroll
        for (int j = 0; j < 4; ++j) {
            f32x4 z = {0.f, 0.f, 0.f, 0.f};
            acc[i][j] = z;
        }

    // Staging geometry: tile = 128 rows x 64 B; wave DMAs two 1-KB chunks per
    // matrix; LDS dest = wave-uniform base + lane*16 (HW rule).
    const int lin0 = (wave * 2) * 1024 + lane * 16;
    const int lin1 = lin0 + 1024;
    const int row0 = lin0 >> 6, col0 = (lin0 & 63) >> 1;   // shorts
    const int row1 = lin1 >> 6, col1 = (lin1 & 63) >> 1;
    int ga0 = m0 + row0; if (ga0 >= M) ga0 = M - 1;        // clamp; rows >= M never stored
    int ga1 = m0 + row1; if (ga1 >= M) ga1 = M - 1;
    const int gb0 = n0 + row0, gb1 = n0 + row1;            // N % 128 == 0

    const unsigned short* pa0 = A + (size_t)ga0 * K + col0;
    const unsigned short* pa1 = A + (size_t)ga1 * K + col1;
    const unsigned short* pb0 = B + (size_t)gb0 * K + col0;
    const unsigned short* pb1 = B + (size_t)gb1 * K + col1;
    lds_uint* la0 = (lds_uint*)&lsA[(wave * 2) * 512];
    lds_uint* la1 = (lds_uint*)&lsA[(wave * 2 + 1) * 512];
    lds_uint* lb0 = (lds_uint*)&lsB[(wave * 2) * 512];
    lds_uint* lb1 = (lds_uint*)&lsB[(wave * 2 + 1) * 512];

    for (int k0 = 0; k0 < K; k0 += 32) {
        __syncthreads();
        __builtin_amdgcn_global_load_lds((global_cuint*)(pa0 + k0), la0, 16, 0, 0);
        __builtin_amdgcn_global_load_lds((global_cuint*)(pa1 + k0), la1, 16, 0, 0);
        __builtin_amdgcn_global_load_lds((global_cuint*)(pb0 + k0), lb0, 16, 0, 0);
        __builtin_amdgcn_global_load_lds((global_cuint*)(pb1 + k0), lb1, 16, 0, 0);
        __syncthreads();
        bf16x8 av[4], bv[4];
#pragma unroll
        for (int mi = 0; mi < 4; ++mi)
            av[mi] = *(const bf16x8*)(&lsA[(wr + mi * 16 + fr) * 32 + kof]);
#pragma unroll
        for (int ni = 0; ni < 4; ++ni)
            bv[ni] = *(const bf16x8*)(&lsB[(wc + ni * 16 + fr) * 32 + kof]);
#pragma unroll
        for (int mi = 0; mi < 4; ++mi)
#pragma unroll
            for (int ni = 0; ni < 4; ++ni)
                acc[mi][ni] = __builtin_amdgcn_mfma_f32_16x16x32_bf16(av[mi], bv[ni], acc[mi][ni], 0, 0, 0);
    }

    float s1 = 0.f, s2 = 0.f;
#pragma unroll
    for (int mi = 0; mi < 4; ++mi) {
#pragma unroll
        for (int r = 0; r < 4; ++r) {
            int row = m0 + wr + mi * 16 + quad * 4 + r;   // D: row = quad*4 + reg
            if (row >= M) continue;
#pragma unroll
            for (int ni = 0; ni < 4; ++ni) {
                int col = n0 + wc + ni * 16 + fr;          // D: col = lane & 15
                float v = acc[mi][ni][r];
                if (bias) v += bias[col];
                if (relu) v = fmaxf(v, 0.f);
                if (redslot >= 0) { s1 += v; s2 += v * v; }
                if (Cb) Cb[(size_t)row * N + col] = f2bf(v);
                else    Cf[(size_t)row * N + col] = v;
            }
        }
    }

    if (redslot >= 0) {
        __syncthreads();
        float* sm = (float*)lsA;
        sm[tid] = s1;
        sm[256 + tid] = s2;
        __syncthreads();
        for (int o = 128; o > 0; o >>= 1) {
            if (tid < o) {
                sm[tid] += sm[tid + o];
                sm[256 + tid] += sm[256 + tid + o];
            }
            __syncthreads();
        }
        if (tid == 0) {
            atomicAdd(&accg[redslot * 2], sm[0]);
            atomicAdd(&accg[redslot * 2 + 1], sm[256]);
        }
    }
}

// ---------------- GRU gate combine (gh + hprev in bf16), vectorized ----------------
__global__ void k_combine(const float4* __restrict__ gi, const ushort4* __restrict__ gh,
                          const int* __restrict__ pair, const ushort4* __restrict__ hprev,
                          ushort4* __restrict__ hout) {
    int idx = blockIdx.x * blockDim.x + threadIdx.x;       // 4-elem units
    if (idx >= P_PAIRS * (HSZ / 4)) return;
    int p = idx >> 9;                                       // HSZ/4 = 512
    int c4 = idx & 511;
    int node = pair[p];
    const float4* gip = gi + (size_t)node * (G3H / 4) + c4;
    const ushort4* ghp = gh + (size_t)p * (G3H / 4) + c4;
    float4 gir = gip[0],   giz = gip[512], gin = gip[1024];
    ushort4 ghr4 = ghp[0], ghz4 = ghp[512], ghn4 = ghp[1024];
    float hr[4] = {bf2f(ghr4.x), bf2f(ghr4.y), bf2f(ghr4.z), bf2f(ghr4.w)};
    float hz[4] = {bf2f(ghz4.x), bf2f(ghz4.y), bf2f(ghz4.z), bf2f(ghz4.w)};
    float hn[4] = {bf2f(ghn4.x), bf2f(ghn4.y), bf2f(ghn4.z), bf2f(ghn4.w)};
    ushort4 h = hprev[idx];
    float hp[4] = {bf2f(h.x), bf2f(h.y), bf2f(h.z), bf2f(h.w)};
    float ir[4] = {gir.x, gir.y, gir.z, gir.w};
    float iz[4] = {giz.x, giz.y, giz.z, giz.w};
    float in_[4] = {gin.x, gin.y, gin.z, gin.w};
    unsigned short o[4];
#pragma unroll
    for (int q = 0; q < 4; ++q) {
        float r = sigm(ir[q] + hr[q]);
        float z = sigm(iz[q] + hz[q]);
        float nn = tanhf(in_[q] + r * hn[q]);
        o[q] = f2bf((1.f - z) * nn + z * hp[q]);
    }
    ushort4 ov = {o[0], o[1], o[2], o[3]};
    hout[idx] = ov;
}

// ---------------- apply full-tensor LN (bf16 t in), emit bf16 ----------------
__global__ void k_lnapply(const ushort4* __restrict__ t, const float4* __restrict__ w,
                          const float4* __restrict__ b, const float* __restrict__ acc, int slot,
                          int n, ushort4* __restrict__ out) {
    float cnt = (float)n;
    float mu = acc[slot * 2] / cnt;
    float var = acc[slot * 2 + 1] / cnt - mu * mu;
    float inv = rsqrtf(var + LN_EPS);
    int n4 = n >> 2;
    int idx = blockIdx.x * blockDim.x + threadIdx.x;
    int stride = gridDim.x * blockDim.x;
    for (; idx < n4; idx += stride) {
        ushort4 tv = t[idx];
        float4 wv = w[idx], bv = b[idx];
        ushort4 o;
        o.x = f2bf((bf2f(tv.x) - mu) * inv * wv.x + bv.x);
        o.y = f2bf((bf2f(tv.y) - mu) * inv * wv.y + bv.y);
        o.z = f2bf((bf2f(tv.z) - mu) * inv * wv.z + bv.z);
        o.w = f2bf((bf2f(tv.w) - mu) * inv * wv.w + bv.w);
        out[idx] = o;
    }
}

// ---------------- head: LN3 fused + sigmoid(W4 . h + b4) + symmetric scatter ----------------
// One wave per pair row; lane0 writes both triangles; waves < NNODES zero the diagonal.
__global__ void k_head(const unsigned short* __restrict__ t, const float* __restrict__ w,
                       const float* __restrict__ b, const float* __restrict__ accv,
                       const float* __restrict__ W4, const float* __restrict__ b4,
                       const int* __restrict__ ip, const int* __restrict__ jp,
                       float* __restrict__ out) {
    int wid = (blockIdx.x * blockDim.x + threadIdx.x) >> 6;
    int lane = threadIdx.x & 63;
    if (wid >= P_PAIRS) return;
    if (lane == 0 && wid < NNODES) out[wid * NNODES + wid] = 0.f;
    float cnt = (float)P_PAIRS * (float)H2SZ;
    float mu = accv[4] / cnt;
    float var = accv[5] / cnt - mu * mu;
    float inv = rsqrtf(var + LN_EPS);
    const unsigned short* row = t + (size_t)wid * H2SZ;
    const float* wrp = w + (size_t)wid * H2SZ;
    const float* brp = b + (size_t)wid * H2SZ;
    float s = 0.f;
    for (int k = lane; k < H2SZ; k += 64)
        s += ((bf2f(row[k]) - mu) * inv * wrp[k] + brp[k]) * W4[k];
#pragma unroll
    for (int o = 32; o > 0; o >>= 1) s += __shfl_down(s, o, 64);
    if (lane == 0) {
        float v = sigm(s + b4[0]);
        int i = ip[wid], j = jp[wid];
        out[i * NNODES + j] = v;
        out[j * NNODES + i] = v;
    }
}

extern "C" void kernel_launch(void* const* d_in, const int* in_sizes, int n_in,
                              void* d_out, int out_size, void* d_ws, size_t ws_size,
                              hipStream_t stream) {
    const float* x    = (const float*)d_in[0];
    const float* hid  = (const float*)d_in[1];
    const float* Wih  = (const float*)d_in[2];
    const float* Whh  = (const float*)d_in[3];
    const float* bih  = (const float*)d_in[4];
    const float* bhh  = (const float*)d_in[5];
    const float* W1   = (const float*)d_in[6];
    const float* b1   = (const float*)d_in[7];
    const float* ln1w = (const float*)d_in[8];
    const float* ln1b = (const float*)d_in[9];
    const float* W2   = (const float*)d_in[10];
    const float* b2   = (const float*)d_in[11];
    const float* ln2w = (const float*)d_in[12];
    const float* ln2b = (const float*)d_in[13];
    const float* W3   = (const float*)d_in[14];
    const float* b3   = (const float*)d_in[15];
    const float* ln3w = (const float*)d_in[16];
    const float* ln3b = (const float*)d_in[17];
    const float* W4   = (const float*)d_in[18];
    const float* b4   = (const float*)d_in[19];
    float* out = (float*)d_out;

    char* ws = (char*)d_ws;
    size_t off = 0;
    auto alloc = [&](size_t bytes) -> void* {
        off = (off + 255) & ~(size_t)255;
        void* p = ws + off;
        off += bytes;
        return p;
    };

    float* acc            = (float*)alloc(8 * sizeof(float));
    int*   ip             = (int*)alloc(P_PAIRS * sizeof(int));
    int*   jp             = (int*)alloc(P_PAIRS * sizeof(int));
    float* gi             = (float*)alloc((size_t)NNODES * G3H * sizeof(float));
    unsigned short* whh_b = (unsigned short*)alloc((size_t)G3H * HSZ * 2);
    unsigned short* w1_b  = (unsigned short*)alloc((size_t)HSZ * HSZ * 2);
    unsigned short* w2_b  = (unsigned short*)alloc((size_t)H2SZ * HSZ * 2);
    unsigned short* w3_b  = (unsigned short*)alloc((size_t)H2SZ * H2SZ * 2);
    unsigned short* hid_b = (unsigned short*)alloc((size_t)P_PAIRS * HSZ * 2); // reused as LN bf16 buf
    unsigned short* hbuf  = (unsigned short*)alloc((size_t)P_PAIRS * HSZ * 2); // h1 then h2 (in-place)
    unsigned short* gh    = (unsigned short*)alloc((size_t)P_PAIRS * G3H * 2); // bf16 gates
    unsigned short* t_b   = (unsigned short*)alloc((size_t)P_PAIRS * HSZ * 2); // bf16 LN input
    (void)ws_size; (void)in_sizes; (void)n_in; (void)out_size;

    unsigned short* lnb = hid_b; // alias: hid_b consumed (GEMM #1 + combine #1) before LN1 apply

    k_prep<<<2048, 256, 0, stream>>>((const float4*)Whh, (ushort4*)whh_b,
                                     (const float4*)W1, (ushort4*)w1_b,
                                     (const float4*)W2, (ushort4*)w2_b,
                                     (const float4*)W3, (ushort4*)w3_b,
                                     (const float4*)hid, (ushort4*)hid_b,
                                     ip, jp, acc, x, Wih, bih, gi);

    dim3 gBig((P_PAIRS + 127) / 128, G3H / 128);   // 28 x 48
    dim3 g3((P_PAIRS + 127) / 128, HSZ / 128);     // 28 x 16
    dim3 g4((P_PAIRS + 127) / 128, H2SZ / 128);    // 28 x 8
    int cgrid = (P_PAIRS * HSZ / 4 + 255) / 256;

    // GRU step 1: gh = hid @ Whh^T + bhh (bf16 out)
    k_gemm<<<gBig, 256, 0, stream>>>(hid_b, whh_b, bhh, nullptr, gh, P_PAIRS, G3H, HSZ, 0, acc, -1);
    k_combine<<<cgrid, 256, 0, stream>>>((const float4*)gi, (const ushort4*)gh, ip,
                                         (const ushort4*)hid_b, (ushort4*)hbuf);
    // GRU step 2: gh = h1 @ Whh^T + bhh (bf16 out)
    k_gemm<<<gBig, 256, 0, stream>>>(hbuf, whh_b, bhh, nullptr, gh, P_PAIRS, G3H, HSZ, 0, acc, -1);
    k_combine<<<cgrid, 256, 0, stream>>>((const float4*)gi, (const ushort4*)gh, jp,
                                         (const ushort4*)hbuf, (ushort4*)hbuf);

    // Layer 1: t = relu(h2 @ W1^T + b1) (bf16); sum/sumsq fused; LN -> lnb
    k_gemm<<<g3, 256, 0, stream>>>(hbuf, w1_b, b1, nullptr, t_b, P_PAIRS, HSZ, HSZ, 1, acc, 0);
    k_lnapply<<<2048, 256, 0, stream>>>((const ushort4*)t_b, (const float4*)ln1w, (const float4*)ln1b,
                                        acc, 0, P_PAIRS * HSZ, (ushort4*)lnb);

    // Layer 2
    k_gemm<<<g4, 256, 0, stream>>>(lnb, w2_b, b2, nullptr, t_b, P_PAIRS, H2SZ, HSZ, 1, acc, 1);
    k_lnapply<<<2048, 256, 0, stream>>>((const ushort4*)t_b, (const float4*)ln2w, (const float4*)ln2b,
                                        acc, 1, P_PAIRS * H2SZ, (ushort4*)lnb);

    // Layer 3
    k_gemm<<<g4, 256, 0, stream>>>(lnb, w3_b, b3, nullptr, t_b, P_PAIRS, H2SZ, H2SZ, 1, acc, 2);

    // Head: LN3 fused + W4 matvec + sigmoid + symmetric scatter (incl. diagonal)
    k_head<<<(P_PAIRS * 64 + 255) / 256, 256, 0, stream>>>(t_b, ln3w, ln3b, acc, W4, b4, ip, jp, out);
}